// Round 1
// baseline (1486.039 us; speedup 1.0000x reference)
//
#include <hip/hip_runtime.h>
#include <math.h>

#define BATCH 4
#define SEQ   1025
#define CH    768
#define HEADS 12
#define DHEAD 64
#define NTOK  1024
#define QKSCALE 0.125f

// workspace layout (float offsets)
#define QKV_OFF 0ull
#define QKV_SZ  ((size_t)BATCH*SEQ*3*CH)
#define XO_OFF  (QKV_OFF + QKV_SZ)
#define XO_SZ   ((size_t)BATCH*SEQ*CH)
#define CLS_OFF (XO_OFF + XO_SZ)
#define CLS_SZ  ((size_t)2*BATCH*CH)
#define QSIM_OFF (CLS_OFF + CLS_SZ)
#define QSIM_SZ ((size_t)BATCH*NTOK)
#define MASK_OFF (QSIM_OFF + QSIM_SZ)

// ---------------- fp32 tiled GEMM: C[M,N] = A[M,K] * B[K,N] (+bias) ----------------
__global__ __launch_bounds__(256) void gemm_f32(
    const float* __restrict__ A, const float* __restrict__ Bm,
    const float* __restrict__ bias, float* __restrict__ Cm,
    int M, int K, int Nn, int useBias)
{
    __shared__ float As[16][68];   // [kk][mm], padded for b128 alignment
    __shared__ float Bs[16][64];   // [kk][nn]
    int t = threadIdx.x;
    int m0 = blockIdx.y * 64, n0 = blockIdx.x * 64;
    int ty = t >> 4, tx = t & 15;
    int laRow = t >> 2, laK = (t & 3) * 4;
    int lbK = t >> 4, lbN = (t & 15) * 4;
    float acc[4][4] = {};
    for (int k0 = 0; k0 < K; k0 += 16) {
        float4 av = make_float4(0.f, 0.f, 0.f, 0.f);
        int arow = m0 + laRow;
        if (arow < M) av = *(const float4*)(A + (size_t)arow * K + k0 + laK);
        As[laK + 0][laRow] = av.x; As[laK + 1][laRow] = av.y;
        As[laK + 2][laRow] = av.z; As[laK + 3][laRow] = av.w;
        *(float4*)&Bs[lbK][lbN] =
            *(const float4*)(Bm + (size_t)(k0 + lbK) * Nn + n0 + lbN);
        __syncthreads();
        #pragma unroll
        for (int kk = 0; kk < 16; ++kk) {
            float4 a4 = *(const float4*)&As[kk][ty * 4];
            float4 b4 = *(const float4*)&Bs[kk][tx * 4];
            float a[4] = {a4.x, a4.y, a4.z, a4.w};
            float b[4] = {b4.x, b4.y, b4.z, b4.w};
            #pragma unroll
            for (int i = 0; i < 4; ++i)
                #pragma unroll
                for (int j = 0; j < 4; ++j) acc[i][j] += a[i] * b[j];
        }
        __syncthreads();
    }
    #pragma unroll
    for (int i = 0; i < 4; ++i) {
        int row = m0 + ty * 4 + i;
        if (row >= M) continue;
        #pragma unroll
        for (int j = 0; j < 4; ++j) {
            float v = acc[i][j];
            int col = n0 + tx * 4 + j;
            if (useBias) v += bias[col];
            Cm[(size_t)row * Nn + col] = v;
        }
    }
}

// ---------------- q_sim raw: per (b, body-token) cosine-sim mean over heads ----------------
__global__ __launch_bounds__(64) void qsim_kernel(
    const float* __restrict__ qkv, const float* __restrict__ g, float* __restrict__ qsim)
{
    int idx = blockIdx.x;           // 0..B*NTOK-1
    int b = idx >> 10, j = idx & 1023, n = j + 1;
    int lane = threadIdx.x;         // d within head
    const float* qrow = qkv + (size_t)(b * SEQ + n) * (3 * CH);
    float acc = 0.f;
    for (int h = 0; h < HEADS; ++h) {
        float qv = qrow[h * 64 + lane];
        float gv = g[h * 64 + lane];     // g_info[0][0] = first 768 floats
        float sqg = qv * gv, sqq = qv * qv, sgg = gv * gv;
        #pragma unroll
        for (int off = 32; off; off >>= 1) {
            sqg += __shfl_xor(sqg, off);
            sqq += __shfl_xor(sqq, off);
            sgg += __shfl_xor(sgg, off);
        }
        acc += sqg / sqrtf(sqq * sgg);
    }
    if (lane == 0) qsim[idx] = acc * (1.0f / HEADS);
}

// ---------------- global min/max normalize + masks ----------------
__global__ __launch_bounds__(1024) void mask_kernel(
    const float* __restrict__ qsim, unsigned char* __restrict__ posm,
    unsigned char* __restrict__ keepp, unsigned char* __restrict__ keepn)
{
    __shared__ float wmin[16], wmax[16];
    int t = threadIdx.x;            // 0..1023 = body token j
    float v[4];
    float lmin = 1e30f, lmax = -1e30f;
    #pragma unroll
    for (int b = 0; b < 4; ++b) {
        v[b] = qsim[b * NTOK + t];
        lmin = fminf(lmin, v[b]); lmax = fmaxf(lmax, v[b]);
    }
    #pragma unroll
    for (int off = 32; off; off >>= 1) {
        lmin = fminf(lmin, __shfl_xor(lmin, off));
        lmax = fmaxf(lmax, __shfl_xor(lmax, off));
    }
    int wid = t >> 6;
    if ((t & 63) == 0) { wmin[wid] = lmin; wmax[wid] = lmax; }
    __syncthreads();
    if (t == 0) {
        float gmin = wmin[0], gmax = wmax[0];
        for (int i = 1; i < 16; ++i) { gmin = fminf(gmin, wmin[i]); gmax = fmaxf(gmax, wmax[i]); }
        wmin[0] = gmin; wmax[0] = gmax;
    }
    __syncthreads();
    float gmin = wmin[0], gmax = wmax[0];
    float den = gmax - gmin;
    int anyp = 0, anyn = 0;
    #pragma unroll
    for (int b = 0; b < 4; ++b) {
        float s = (v[b] - gmin) / den;           // exact-division to match reference rounding
        int p = s > 0.9f ? 1 : 0;
        posm[b * NTOK + t] = (unsigned char)p;
        anyp |= p; anyn |= (1 - p);
    }
    keepp[t] = (unsigned char)anyp;
    keepn[t] = (unsigned char)anyn;
}

// ---------------- fused grouped flash-attention (fp32) ----------------
// Virtual queries per (b,h): vq=0 -> CLS with pos group, vq=1 -> CLS with neg group,
// vq=2..1025 -> token n=vq-1 with its selected group (keep_neg[n-1] ? neg : pos).
__global__ __launch_bounds__(256) void attn_kernel(
    const float* __restrict__ qkv,
    const unsigned char* __restrict__ posm,
    const unsigned char* __restrict__ keepp,
    const unsigned char* __restrict__ keepn,
    float* __restrict__ xo, float* __restrict__ cls)
{
    __shared__ float qs[16][68];
    __shared__ float ks[64][68];
    __shared__ float vs[64][68];
    __shared__ float ps[16][68];
    __shared__ float m_st[16], l_st[16], alpha_st[16];
    __shared__ float qmq[16];
    __shared__ int   qn[16];
    __shared__ unsigned char qgrp[16], qval[16];
    __shared__ unsigned char mk[2][64];   // [grp][key-in-tile] value mask (m)
    __shared__ unsigned char kp[2][64];   // [grp][key-in-tile] key_keep

    int t = threadIdx.x;
    int b = blockIdx.y / HEADS, h = blockIdx.y % HEADS;
    int vq0 = blockIdx.x * 16;
    int qi = t >> 4, d4 = (t & 15) * 4;

    if (t < 16) {
        int vq = vq0 + t;
        int n = 0, grp = 0, valid = 1; float mq = 1.f;
        if (vq <= 1) { grp = vq; }
        else if (vq <= SEQ) {
            n = vq - 1; int j = n - 1;
            grp = keepn[j] ? 1 : 0;
            int p = posm[b * NTOK + j];
            mq = (float)(grp ? (1 - p) : p);
        } else { valid = 0; mq = 0.f; }
        qn[t] = n; qgrp[t] = (unsigned char)grp; qmq[t] = mq;
        qval[t] = (unsigned char)valid;
        m_st[t] = -INFINITY; l_st[t] = 0.f; alpha_st[t] = 1.f;
    }
    __syncthreads();

    {   // load Q tile (query mask folded in)
        float4 qv = make_float4(0.f, 0.f, 0.f, 0.f);
        if (qval[qi]) {
            const float* qr = qkv + (size_t)(b * SEQ + qn[qi]) * (3 * CH) + h * DHEAD + d4;
            qv = *(const float4*)qr;
            float mq = qmq[qi];
            qv.x *= mq; qv.y *= mq; qv.z *= mq; qv.w *= mq;
        }
        qs[qi][d4 + 0] = qv.x; qs[qi][d4 + 1] = qv.y;
        qs[qi][d4 + 2] = qv.z; qs[qi][d4 + 3] = qv.w;
    }

    float acc0 = 0.f, acc1 = 0.f, acc2 = 0.f, acc3 = 0.f;

    for (int k0 = 0; k0 < SEQ; k0 += 64) {
        __syncthreads();
        {   // load K/V tile + per-key masks
            int rb = t >> 4, c4 = (t & 15) * 4;
            #pragma unroll
            for (int rep = 0; rep < 4; ++rep) {
                int row = rb + rep * 16;
                int jk = k0 + row;
                float4 kv = make_float4(0, 0, 0, 0), vv = make_float4(0, 0, 0, 0);
                if (jk < SEQ) {
                    const float* base = qkv + (size_t)(b * SEQ + jk) * (3 * CH) + h * DHEAD + c4;
                    kv = *(const float4*)(base + CH);
                    vv = *(const float4*)(base + 2 * CH);
                }
                ks[row][c4 + 0] = kv.x; ks[row][c4 + 1] = kv.y;
                ks[row][c4 + 2] = kv.z; ks[row][c4 + 3] = kv.w;
                vs[row][c4 + 0] = vv.x; vs[row][c4 + 1] = vv.y;
                vs[row][c4 + 2] = vv.z; vs[row][c4 + 3] = vv.w;
            }
            if (t < 64) {
                int jk = k0 + t;
                unsigned char mp = 0, mn = 0, cp = 0, cn = 0;
                if (jk == 0) { mp = mn = cp = cn = 1; }
                else if (jk < SEQ) {
                    int j = jk - 1;
                    unsigned char p = posm[b * NTOK + j];
                    mp = p; mn = (unsigned char)(1 - p);
                    cp = keepp[j]; cn = keepn[j];
                }
                mk[0][t] = mp; mk[1][t] = mn; kp[0][t] = cp; kp[1][t] = cn;
            }
        }
        __syncthreads();
        {   // S = (q_eff . k) * scale * mk, gated by key_keep
            int sqi = t & 15;
            int kb = (t >> 4) * 4;
            float dot[4] = {0.f, 0.f, 0.f, 0.f};
            #pragma unroll
            for (int d = 0; d < 16; ++d) {
                float4 qv = *(const float4*)&qs[sqi][d * 4];
                #pragma unroll
                for (int u = 0; u < 4; ++u) {
                    float4 kv = *(const float4*)&ks[kb + u][d * 4];
                    dot[u] += qv.x * kv.x + qv.y * kv.y + qv.z * kv.z + qv.w * kv.w;
                }
            }
            int grp = qgrp[sqi];
            #pragma unroll
            for (int u = 0; u < 4; ++u) {
                int kk = kb + u;
                float sv = kp[grp][kk] ? dot[u] * QKSCALE * (float)mk[grp][kk] : -INFINITY;
                ps[sqi][kk] = sv;
            }
        }
        __syncthreads();
        // online-softmax row update (note: row-sum l includes masked-but-kept keys, exp(0))
        if (t < 64) {
            int r = t >> 2, seg = t & 3;
            float lm = -INFINITY;
            #pragma unroll
            for (int u = 0; u < 16; ++u) lm = fmaxf(lm, ps[r][seg * 16 + u]);
            lm = fmaxf(lm, __shfl_xor(lm, 1));
            lm = fmaxf(lm, __shfl_xor(lm, 2));
            float mold = m_st[r];
            float mnew = fmaxf(mold, lm);
            float lsum = 0.f;
            float alpha = 1.f;
            if (mnew == -INFINITY) {
                #pragma unroll
                for (int u = 0; u < 16; ++u) ps[r][seg * 16 + u] = 0.f;
            } else {
                alpha = expf(mold - mnew);   // mold=-inf -> 0
                #pragma unroll
                for (int u = 0; u < 16; ++u) {
                    float s = ps[r][seg * 16 + u];
                    float p = (s == -INFINITY) ? 0.f : expf(s - mnew);
                    ps[r][seg * 16 + u] = p;
                    lsum += p;
                }
            }
            lsum += __shfl_xor(lsum, 1);
            lsum += __shfl_xor(lsum, 2);
            if (seg == 0) {
                l_st[r] = l_st[r] * alpha + lsum;
                m_st[r] = mnew;
                alpha_st[r] = alpha;
            }
        }
        __syncthreads();
        {   // PV accumulate (value mask folded here, not in l)
            float a = alpha_st[qi];
            acc0 *= a; acc1 *= a; acc2 *= a; acc3 *= a;
            int grp = qgrp[qi];
            const unsigned char* mkg = mk[grp];
            for (int j = 0; j < 64; ++j) {
                float pm = ps[qi][j] * (float)mkg[j];
                float4 vv = *(const float4*)&vs[j][d4];
                acc0 += pm * vv.x; acc1 += pm * vv.y;
                acc2 += pm * vv.z; acc3 += pm * vv.w;
            }
        }
    }

    if (qval[qi]) {
        int vq = vq0 + qi;
        float invl = 1.f / l_st[qi];
        float o0 = acc0 * invl, o1 = acc1 * invl, o2 = acc2 * invl, o3 = acc3 * invl;
        float* dst;
        if (vq >= 2) {
            int n = vq - 1;
            dst = xo + (size_t)(b * SEQ + n) * CH + h * DHEAD + d4;
        } else {
            dst = cls + ((size_t)vq * BATCH + b) * CH + h * DHEAD + d4;
        }
        dst[0] = o0; dst[1] = o1; dst[2] = o2; dst[3] = o3;
    }
}

// ---------------- CLS combine: xo row n=0 per batch = 0.5*(pos + neg) ----------------
__global__ __launch_bounds__(768) void cls_combine(
    const float* __restrict__ cls, float* __restrict__ xo)
{
    int b = blockIdx.x, c = threadIdx.x;
    float v = 0.5f * (cls[(size_t)b * CH + c] + cls[(size_t)(BATCH + b) * CH + c]);
    xo[(size_t)b * SEQ * CH + c] = v;
}

extern "C" void kernel_launch(void* const* d_in, const int* in_sizes, int n_in,
                              void* d_out, int out_size, void* d_ws, size_t ws_size,
                              hipStream_t stream) {
    const float* x      = (const float*)d_in[0];
    const float* g_info = (const float*)d_in[1];
    const float* w_qkv  = (const float*)d_in[2];
    const float* w_proj = (const float*)d_in[3];
    const float* b_proj = (const float*)d_in[4];
    float* out = (float*)d_out;
    float* wsf = (float*)d_ws;

    float* qkv  = wsf + QKV_OFF;
    float* xo   = wsf + XO_OFF;
    float* cls  = wsf + CLS_OFF;
    float* qsim = wsf + QSIM_OFF;
    unsigned char* posm  = (unsigned char*)(wsf + MASK_OFF);
    unsigned char* keepp = posm + (size_t)BATCH * NTOK;
    unsigned char* keepn = keepp + NTOK;

    int M = BATCH * SEQ;   // 4100

    // 1. qkv = x @ w_qkv  (fp32 to keep the data-dependent mask derivation exact)
    gemm_f32<<<dim3(3 * CH / 64, (M + 63) / 64), 256, 0, stream>>>(
        x, w_qkv, nullptr, qkv, M, CH, 3 * CH, 0);
    // 2. raw q_sim per (b, body token)
    qsim_kernel<<<BATCH * NTOK, 64, 0, stream>>>(qkv, g_info, qsim);
    // 3. global min/max normalize + group/keep masks
    mask_kernel<<<1, 1024, 0, stream>>>(qsim, posm, keepp, keepn);
    // 4. grouped flash attention (selected group per token; both groups for CLS)
    attn_kernel<<<dim3(65, BATCH * HEADS), 256, 0, stream>>>(
        qkv, posm, keepp, keepn, xo, cls);
    // 5. CLS rows = average of the two groups
    cls_combine<<<BATCH, CH, 0, stream>>>(cls, xo);
    // 6. out0 = xo @ w_proj + b_proj
    gemm_f32<<<dim3(CH / 64, (M + 63) / 64), 256, 0, stream>>>(
        xo, w_proj, b_proj, out, M, CH, CH, 1);
    // 7. out1 = g_info[1:]
    hipMemcpyAsync(out + (size_t)M * CH, g_info + 2 * CH, (size_t)2 * CH * sizeof(float),
                   hipMemcpyDeviceToDevice, stream);
}

// Round 3
// 404.983 us; speedup vs baseline: 3.6694x; 3.6694x over previous
//
#include <hip/hip_runtime.h>
#include <math.h>

typedef unsigned short ushort_t;
typedef short s16x8 __attribute__((ext_vector_type(8)));
typedef float f32x4 __attribute__((ext_vector_type(4)));

#define MFMA16(a, b, c) __builtin_amdgcn_mfma_f32_16x16x32_bf16(a, b, c, 0, 0, 0)

#define BATCH 4
#define SEQ   1025
#define CH    768
#define HEADS 12
#define NBH   48
#define NKPAD 1088
#define MROWS 4100
#define QKSCALE 0.125f

__device__ __forceinline__ ushort_t f2bf(float f) {
    unsigned u = __builtin_bit_cast(unsigned, f);
    u += 0x7FFFu + ((u >> 16) & 1u);
    return (ushort_t)(u >> 16);
}

// ---------------- fp32 tiled GEMM (q only): qf = x @ w_qkv[:, :768] ----------------
// Kept bit-identical in summation order to round 1 so the data-dependent mask bits
// (q_sim > 0.9 after min-max normalize) stay exactly reproducible.
__global__ __launch_bounds__(256) void gemm_f32(
    const float* __restrict__ A, const float* __restrict__ Bm,
    float* __restrict__ Cm, int M, int K, int ldb, int Nn)
{
    __shared__ float As[16][68];
    __shared__ float Bs[16][64];
    int t = threadIdx.x;
    int m0 = blockIdx.y * 64, n0 = blockIdx.x * 64;
    int ty = t >> 4, tx = t & 15;
    int laRow = t >> 2, laK = (t & 3) * 4;
    int lbK = t >> 4, lbN = (t & 15) * 4;
    float acc[4][4] = {};
    for (int k0 = 0; k0 < K; k0 += 16) {
        float4 av = make_float4(0.f, 0.f, 0.f, 0.f);
        int arow = m0 + laRow;
        if (arow < M) av = *(const float4*)(A + (size_t)arow * K + k0 + laK);
        As[laK + 0][laRow] = av.x; As[laK + 1][laRow] = av.y;
        As[laK + 2][laRow] = av.z; As[laK + 3][laRow] = av.w;
        *(float4*)&Bs[lbK][lbN] =
            *(const float4*)(Bm + (size_t)(k0 + lbK) * ldb + n0 + lbN);
        __syncthreads();
        #pragma unroll
        for (int kk = 0; kk < 16; ++kk) {
            float4 a4 = *(const float4*)&As[kk][ty * 4];
            float4 b4 = *(const float4*)&Bs[kk][tx * 4];
            float a[4] = {a4.x, a4.y, a4.z, a4.w};
            float b[4] = {b4.x, b4.y, b4.z, b4.w};
            #pragma unroll
            for (int i = 0; i < 4; ++i)
                #pragma unroll
                for (int j = 0; j < 4; ++j) acc[i][j] += a[i] * b[j];
        }
        __syncthreads();
    }
    #pragma unroll
    for (int i = 0; i < 4; ++i) {
        int row = m0 + ty * 4 + i;
        if (row >= M) continue;
        #pragma unroll
        for (int j = 0; j < 4; ++j)
            Cm[(size_t)row * Nn + n0 + tx * 4 + j] = acc[i][j];
    }
}

// ---------------- x f32 -> bf16 ----------------
__global__ __launch_bounds__(256) void convx(const float* __restrict__ x,
                                             ushort_t* __restrict__ xb, int n4)
{
    int i = blockIdx.x * 256 + threadIdx.x;
    if (i >= n4) return;
    float4 v = ((const float4*)x)[i];
    ushort_t o[4] = {f2bf(v.x), f2bf(v.y), f2bf(v.z), f2bf(v.w)};
    *(uint2*)(xb + (size_t)i * 4) = *(const uint2*)o;
}

// ---------------- transpose + convert: dst[n][k] = bf16(src[k][c0+n]) ----------------
__global__ __launch_bounds__(256) void convT(const float* __restrict__ src, int ld,
                                             int c0, ushort_t* __restrict__ dst)
{
    __shared__ float tile[32][33];
    int k0 = blockIdx.x * 32, n0 = blockIdx.y * 32;
    int t = threadIdx.x, tx = t & 31, ty = t >> 5;
    #pragma unroll
    for (int i = 0; i < 32; i += 8)
        tile[ty + i][tx] = src[(size_t)(k0 + ty + i) * ld + c0 + n0 + tx];
    __syncthreads();
    #pragma unroll
    for (int i = 0; i < 32; i += 8)
        dst[(size_t)(n0 + ty + i) * CH + k0 + tx] = f2bf(tile[tx][ty + i]);
}

// ---------------- bf16 MFMA GEMM: xb @ wkvT^T -> kb (row-major) + vtb (transposed) --------
__global__ __launch_bounds__(256) void kvgemm(
    const ushort_t* __restrict__ xb, const ushort_t* __restrict__ wkvT,
    ushort_t* __restrict__ kbuf, ushort_t* __restrict__ vtbuf)
{
    int t = threadIdx.x, w = t >> 6, l = t & 63;
    int l15 = l & 15, lhi = l >> 4;
    int m0 = blockIdx.x * 64 + 16 * w;
    int n0 = blockIdx.y * 64;
    int ar = m0 + l15; if (ar >= MROWS) ar = MROWS - 1;
    f32x4 acc[4] = {{0,0,0,0},{0,0,0,0},{0,0,0,0},{0,0,0,0}};
    for (int k = 0; k < CH; k += 32) {
        s16x8 af = *(const s16x8*)(xb + (size_t)ar * CH + k + lhi * 8);
        #pragma unroll
        for (int nt = 0; nt < 4; ++nt) {
            s16x8 bf_ = *(const s16x8*)(wkvT + (size_t)(n0 + 16 * nt + l15) * CH + k + lhi * 8);
            acc[nt] = MFMA16(af, bf_, acc[nt]);
        }
    }
    #pragma unroll
    for (int nt = 0; nt < 4; ++nt)
        #pragma unroll
        for (int r = 0; r < 4; ++r) {
            int m = m0 + lhi * 4 + r;
            if (m >= MROWS) continue;
            int b = m / SEQ, tok = m % SEQ;
            int n = n0 + 16 * nt + l15;
            ushort_t val = f2bf(acc[nt][r]);
            if (n < CH) {
                int h = n >> 6, d = n & 63;
                kbuf[((size_t)(b * HEADS + h) * NKPAD + tok) * 64 + d] = val;
            } else {
                int c = n - CH; int h = c >> 6, d = c & 63;
                vtbuf[((size_t)(b * HEADS + h) * 64 + d) * NKPAD + tok] = val;
            }
        }
}

// ---------------- zero the padded key rows/cols (+ padded q rows) ----------------
__global__ __launch_bounds__(256) void zeropad(ushort_t* kbuf, ushort_t* vtbuf, ushort_t* qbuf)
{
    int t = blockIdx.x * 256 + threadIdx.x;
    if (t < NBH * 63 * 64) {  // kb rows 1025..1087
        int bh = t / (63 * 64), rem = t % (63 * 64);
        kbuf[((size_t)bh * NKPAD + 1025 + rem / 64) * 64 + (rem & 63)] = 0;
    }
    if (t < NBH * 64 * 63) {  // vtb cols 1025..1087
        int bh = t / (64 * 63), rem = t % (64 * 63);
        vtbuf[((size_t)bh * 64 + rem / 63) * NKPAD + 1025 + rem % 63] = 0;
    }
    if (t < NBH * 62 * 64) {  // qb rows 1026..1087
        int bh = t / (62 * 64), rem = t % (62 * 64);
        qbuf[((size_t)bh * NKPAD + 1026 + rem / 64) * 64 + (rem & 63)] = 0;
    }
}

// ---------------- q_sim (from fp32 qf) ----------------
__global__ __launch_bounds__(64) void qsim_kernel(
    const float* __restrict__ qf, const float* __restrict__ g, float* __restrict__ qsim)
{
    int idx = blockIdx.x;
    int b = idx >> 10, j = idx & 1023, n = j + 1;
    int lane = threadIdx.x;
    const float* qrow = qf + (size_t)(b * SEQ + n) * CH;
    float acc = 0.f;
    for (int h = 0; h < HEADS; ++h) {
        float qv = qrow[h * 64 + lane];
        float gv = g[h * 64 + lane];
        float sqg = qv * gv, sqq = qv * qv, sgg = gv * gv;
        #pragma unroll
        for (int off = 32; off; off >>= 1) {
            sqg += __shfl_xor(sqg, off);
            sqq += __shfl_xor(sqq, off);
            sgg += __shfl_xor(sgg, off);
        }
        acc += sqg / sqrtf(sqq * sgg);
    }
    if (lane == 0) qsim[idx] = acc * (1.0f / HEADS);
}

// ---------------- min/max normalize + packed masks ----------------
// kmask byte bits: 0=mk_pos, 1=mk_neg, 2=kp_pos, 3=kp_neg
__global__ __launch_bounds__(1024) void mask_kernel(
    const float* __restrict__ qsim, unsigned char* __restrict__ posm,
    unsigned char* __restrict__ kmask, unsigned char* __restrict__ vgrp)
{
    __shared__ float wmin[16], wmax[16];
    int t = threadIdx.x;
    float v[4];
    float lmin = 1e30f, lmax = -1e30f;
    #pragma unroll
    for (int b = 0; b < 4; ++b) {
        v[b] = qsim[b * 1024 + t];
        lmin = fminf(lmin, v[b]); lmax = fmaxf(lmax, v[b]);
    }
    #pragma unroll
    for (int off = 32; off; off >>= 1) {
        lmin = fminf(lmin, __shfl_xor(lmin, off));
        lmax = fmaxf(lmax, __shfl_xor(lmax, off));
    }
    if ((t & 63) == 0) { wmin[t >> 6] = lmin; wmax[t >> 6] = lmax; }
    __syncthreads();
    if (t == 0) {
        float gmin = wmin[0], gmax = wmax[0];
        for (int i = 1; i < 16; ++i) { gmin = fminf(gmin, wmin[i]); gmax = fmaxf(gmax, wmax[i]); }
        wmin[0] = gmin; wmax[0] = gmax;
    }
    __syncthreads();
    float gmin = wmin[0], den = wmax[0] - gmin;
    int pb[4], anyp = 0, anyn = 0;
    #pragma unroll
    for (int b = 0; b < 4; ++b) {
        float s = (v[b] - gmin) / den;
        pb[b] = s > 0.9f ? 1 : 0;
        anyp |= pb[b]; anyn |= (1 - pb[b]);
    }
    #pragma unroll
    for (int b = 0; b < 4; ++b) {
        posm[b * 1024 + t] = (unsigned char)pb[b];
        kmask[b * NKPAD + 1 + t] =
            (unsigned char)(pb[b] | ((pb[b] ^ 1) << 1) | (anyp << 2) | (anyn << 3));
    }
    vgrp[2 + t] = (unsigned char)anyn;
    if (t == 0) {
        vgrp[0] = 0; vgrp[1] = 1;
        #pragma unroll
        for (int b = 0; b < 4; ++b) kmask[b * NKPAD] = 0xF;
    }
    if (t < 62) vgrp[1026 + t] = 0;
    if (t < 63)
        #pragma unroll
        for (int b = 0; b < 4; ++b) kmask[b * NKPAD + 1025 + t] = 0;
}

// ---------------- build virtual-query bf16 buffer (query mask folded in) ----------------
__global__ __launch_bounds__(256) void buildq(
    const float* __restrict__ qf, const unsigned char* __restrict__ posm,
    const unsigned char* __restrict__ vgrp, ushort_t* __restrict__ qbuf)
{
    int bh = blockIdx.y, b = bh / HEADS, h = bh % HEADS;
    int rr = blockIdx.x * 4 + (threadIdx.x >> 6);
    int d = threadIdx.x & 63;
    if (rr > 1025) return;
    int n, mq;
    if (rr < 2) { n = 0; mq = 1; }
    else {
        n = rr - 1; int j = n - 1;
        int g = vgrp[rr];
        int p = posm[b * 1024 + j];
        mq = g ? (1 - p) : p;
    }
    float v = qf[(size_t)(b * SEQ + n) * CH + h * 64 + d] * (float)mq;
    qbuf[((size_t)bh * NKPAD + rr) * 64 + d] = f2bf(v);
}

// ---------------- MFMA grouped flash attention ----------------
__global__ __launch_bounds__(256) void attn_mfma(
    const ushort_t* __restrict__ qb, const ushort_t* __restrict__ kb,
    const ushort_t* __restrict__ vtb, const unsigned char* __restrict__ kmask,
    const unsigned char* __restrict__ vgrp,
    ushort_t* __restrict__ xob, float* __restrict__ clsf)
{
    __shared__ unsigned char kml[NKPAD];
    __shared__ __align__(16) ushort_t plds[4 * 1024];

    int t = threadIdx.x, w = t >> 6, l = t & 63;
    int l15 = l & 15, lhi = l >> 4;
    int bh = blockIdx.y, b = bh / HEADS, h = bh % HEADS;
    int vq0 = blockIdx.x * 64;
    int qrow_base = vq0 + 16 * w;

    for (int i = t; i < NKPAD; i += 256) kml[i] = kmask[b * NKPAD + i];

    unsigned char qg[4];
    #pragma unroll
    for (int r = 0; r < 4; ++r) qg[r] = vgrp[qrow_base + lhi * 4 + r];

    const ushort_t* qptr = qb + ((size_t)bh * NKPAD + qrow_base + l15) * 64 + lhi * 8;
    s16x8 aq0 = *(const s16x8*)qptr;
    s16x8 aq1 = *(const s16x8*)(qptr + 32);

    f32x4 out[4] = {{0,0,0,0},{0,0,0,0},{0,0,0,0},{0,0,0,0}};
    float mrow[4] = {-INFINITY, -INFINITY, -INFINITY, -INFINITY};
    float lrow[4] = {0.f, 0.f, 0.f, 0.f};

    const ushort_t* kbase = kb + (size_t)bh * NKPAD * 64;
    const ushort_t* vbase = vtb + (size_t)bh * 64 * NKPAD;
    int hwb = w * 1024;

    __syncthreads();

    for (int k0 = 0; k0 < NKPAD; k0 += 64) {
        // ---- S = Q K^T ----
        f32x4 s[4];
        #pragma unroll
        for (int tt = 0; tt < 4; ++tt) {
            const ushort_t* kp_ = kbase + (size_t)(k0 + 16 * tt + l15) * 64 + lhi * 8;
            s16x8 bk0 = *(const s16x8*)kp_;
            s16x8 bk1 = *(const s16x8*)(kp_ + 32);
            f32x4 acc = {0, 0, 0, 0};
            acc = MFMA16(aq0, bk0, acc);
            acc = MFMA16(aq1, bk1, acc);
            s[tt] = acc;
        }
        // ---- masks -> logits ----
        unsigned char kbyte[4];
        #pragma unroll
        for (int tt = 0; tt < 4; ++tt) kbyte[tt] = kml[k0 + 16 * tt + l15];
        float p[4][4];
        unsigned pvbits = 0;
        #pragma unroll
        for (int tt = 0; tt < 4; ++tt)
            #pragma unroll
            for (int r = 0; r < 4; ++r) {
                int g = qg[r];
                int mk = (kbyte[tt] >> g) & 1;
                int kpb = (kbyte[tt] >> (2 + g)) & 1;
                float raw = s[tt][r] * QKSCALE;
                float sv = kpb ? (mk ? raw : 0.0f) : -INFINITY;
                p[tt][r] = sv;
                pvbits |= (unsigned)(mk & kpb) << (tt * 4 + r);
            }
        // ---- online softmax ----
        float rm[4], alpha[4], ls[4];
        #pragma unroll
        for (int r = 0; r < 4; ++r) {
            rm[r] = fmaxf(fmaxf(p[0][r], p[1][r]), fmaxf(p[2][r], p[3][r]));
        }
        #pragma unroll
        for (int off = 1; off < 16; off <<= 1)
            #pragma unroll
            for (int r = 0; r < 4; ++r) rm[r] = fmaxf(rm[r], __shfl_xor(rm[r], off));
        #pragma unroll
        for (int r = 0; r < 4; ++r) {
            float mn = fmaxf(mrow[r], rm[r]);
            alpha[r] = __expf(mrow[r] - mn);
            mrow[r] = mn;
            ls[r] = 0.f;
        }
        #pragma unroll
        for (int tt = 0; tt < 4; ++tt)
            #pragma unroll
            for (int r = 0; r < 4; ++r) {
                float pv = __expf(p[tt][r] - mrow[r]);
                p[tt][r] = pv;
                ls[r] += pv;
            }
        #pragma unroll
        for (int off = 1; off < 16; off <<= 1)
            #pragma unroll
            for (int r = 0; r < 4; ++r) ls[r] += __shfl_xor(ls[r], off);
        #pragma unroll
        for (int r = 0; r < 4; ++r) lrow[r] = lrow[r] * alpha[r] + ls[r];
        #pragma unroll
        for (int dt = 0; dt < 4; ++dt)
            #pragma unroll
            for (int r = 0; r < 4; ++r) out[dt][r] *= alpha[r];
        // ---- P (value-masked) -> LDS (bf16, XOR-swizzled) ----
        #pragma unroll
        for (int tt = 0; tt < 4; ++tt)
            #pragma unroll
            for (int r = 0; r < 4; ++r) {
                float pv = ((pvbits >> (tt * 4 + r)) & 1) ? p[tt][r] : 0.f;
                int q = lhi * 4 + r, key = 16 * tt + l15;
                int hw = hwb + ((q * 64 + key) ^ ((q & 7) << 3));
                plds[hw] = f2bf(pv);
            }
        // ---- PV ----
        s16x8 pa0 = *(const s16x8*)&plds[hwb + ((l15 * 64 + lhi * 8) ^ ((l15 & 7) << 3))];
        s16x8 pa1 = *(const s16x8*)&plds[hwb + ((l15 * 64 + 32 + lhi * 8) ^ ((l15 & 7) << 3))];
        #pragma unroll
        for (int dt = 0; dt < 4; ++dt) {
            const ushort_t* vp = vbase + (size_t)(16 * dt + l15) * NKPAD + k0 + lhi * 8;
            s16x8 bv0 = *(const s16x8*)vp;
            s16x8 bv1 = *(const s16x8*)(vp + 32);
            out[dt] = MFMA16(pa0, bv0, out[dt]);
            out[dt] = MFMA16(pa1, bv1, out[dt]);
        }
    }

    // ---- epilogue ----
    float inv[4];
    #pragma unroll
    for (int r = 0; r < 4; ++r) inv[r] = 1.0f / lrow[r];
    #pragma unroll
    for (int dt = 0; dt < 4; ++dt)
        #pragma unroll
        for (int r = 0; r < 4; ++r) {
            int vq = qrow_base + lhi * 4 + r;
            if (vq > 1025) continue;
            int d = 16 * dt + l15;
            float val = out[dt][r] * inv[r];
            if (vq >= 2) {
                int n = vq - 1;
                xob[(size_t)(b * SEQ + n) * CH + h * 64 + d] = f2bf(val);
            } else {
                clsf[(size_t)(vq * BATCH + b) * CH + h * 64 + d] = val;
            }
        }
}

// ---------------- CLS combine into xob row 0 ----------------
__global__ __launch_bounds__(768) void cls_combine(
    const float* __restrict__ clsf, ushort_t* __restrict__ xob)
{
    int b = blockIdx.x, c = threadIdx.x;
    float v = 0.5f * (clsf[(size_t)b * CH + c] + clsf[(size_t)(BATCH + b) * CH + c]);
    xob[(size_t)b * SEQ * CH + c] = f2bf(v);
}

// ---------------- bf16 MFMA projection GEMM: out = xob @ wpT^T + bias (f32 out) --------
__global__ __launch_bounds__(256) void projgemm(
    const ushort_t* __restrict__ xob, const ushort_t* __restrict__ wpT,
    const float* __restrict__ bias, float* __restrict__ outp)
{
    int t = threadIdx.x, w = t >> 6, l = t & 63;
    int l15 = l & 15, lhi = l >> 4;
    int m0 = blockIdx.x * 64 + 16 * w;
    int n0 = blockIdx.y * 64;
    int ar = m0 + l15; if (ar >= MROWS) ar = MROWS - 1;
    f32x4 acc[4] = {{0,0,0,0},{0,0,0,0},{0,0,0,0},{0,0,0,0}};
    for (int k = 0; k < CH; k += 32) {
        s16x8 af = *(const s16x8*)(xob + (size_t)ar * CH + k + lhi * 8);
        #pragma unroll
        for (int nt = 0; nt < 4; ++nt) {
            s16x8 bf_ = *(const s16x8*)(wpT + (size_t)(n0 + 16 * nt + l15) * CH + k + lhi * 8);
            acc[nt] = MFMA16(af, bf_, acc[nt]);
        }
    }
    #pragma unroll
    for (int nt = 0; nt < 4; ++nt)
        #pragma unroll
        for (int r = 0; r < 4; ++r) {
            int m = m0 + lhi * 4 + r;
            if (m >= MROWS) continue;
            int n = n0 + 16 * nt + l15;
            outp[(size_t)m * CH + n] = acc[nt][r] + bias[n];
        }
}

extern "C" void kernel_launch(void* const* d_in, const int* in_sizes, int n_in,
                              void* d_out, int out_size, void* d_ws, size_t ws_size,
                              hipStream_t stream) {
    const float* x      = (const float*)d_in[0];
    const float* g_info = (const float*)d_in[1];
    const float* w_qkv  = (const float*)d_in[2];
    const float* w_proj = (const float*)d_in[3];
    const float* b_proj = (const float*)d_in[4];
    float* out = (float*)d_out;
    char* ws = (char*)d_ws;

    size_t off = 0;
    auto alloc = [&](size_t bytes) { size_t o = off; off += (bytes + 255) & ~(size_t)255; return o; };
    float*    qf    = (float*)(ws + alloc((size_t)MROWS * CH * 4));
    ushort_t* xb    = (ushort_t*)(ws + alloc((size_t)MROWS * CH * 2));
    ushort_t* wkvT  = (ushort_t*)(ws + alloc((size_t)2 * CH * CH * 2));
    ushort_t* wpT   = (ushort_t*)(ws + alloc((size_t)CH * CH * 2));
    ushort_t* kbuf  = (ushort_t*)(ws + alloc((size_t)NBH * NKPAD * 64 * 2));
    ushort_t* vtbuf = (ushort_t*)(ws + alloc((size_t)NBH * NKPAD * 64 * 2));
    ushort_t* qbuf  = (ushort_t*)(ws + alloc((size_t)NBH * NKPAD * 64 * 2));
    ushort_t* xob   = (ushort_t*)(ws + alloc((size_t)MROWS * CH * 2));
    float*    clsf  = (float*)(ws + alloc((size_t)2 * BATCH * CH * 4));
    float*    qsim  = (float*)(ws + alloc((size_t)BATCH * 1024 * 4));
    unsigned char* posm  = (unsigned char*)(ws + alloc((size_t)BATCH * 1024));
    unsigned char* kmask = (unsigned char*)(ws + alloc((size_t)BATCH * NKPAD));
    unsigned char* vgrp  = (unsigned char*)(ws + alloc((size_t)NKPAD));

    // independent prep
    convx<<<(MROWS * CH / 4 + 255) / 256, 256, 0, stream>>>(x, xb, MROWS * CH / 4);
    convT<<<dim3(CH / 32, 2 * CH / 32), 256, 0, stream>>>(w_qkv, 3 * CH, CH, wkvT);
    convT<<<dim3(CH / 32, CH / 32), 256, 0, stream>>>(w_proj, CH, 0, wpT);
    zeropad<<<(NBH * 64 * 63 + 255) / 256, 256, 0, stream>>>(kbuf, vtbuf, qbuf);

    // fp32 q GEMM (mask-exact path)
    gemm_f32<<<dim3(CH / 64, (MROWS + 63) / 64), 256, 0, stream>>>(
        x, w_qkv, qf, MROWS, CH, 3 * CH, CH);
    // bf16 K/V GEMM with layout-transforming stores
    kvgemm<<<dim3((MROWS + 63) / 64, 2 * CH / 64), 256, 0, stream>>>(xb, wkvT, kbuf, vtbuf);

    // masks
    qsim_kernel<<<BATCH * 1024, 64, 0, stream>>>(qf, g_info, qsim);
    mask_kernel<<<1, 1024, 0, stream>>>(qsim, posm, kmask, vgrp);
    buildq<<<dim3(257, NBH), 256, 0, stream>>>(qf, posm, vgrp, qbuf);

    // attention
    attn_mfma<<<dim3(NKPAD / 64, NBH), 256, 0, stream>>>(
        qbuf, kbuf, vtbuf, kmask, vgrp, xob, clsf);
    cls_combine<<<BATCH, CH, 0, stream>>>(clsf, xob);

    // projection
    projgemm<<<dim3((MROWS + 63) / 64, CH / 64), 256, 0, stream>>>(xob, wpT, b_proj, out);

    // tail output: g_info[1:]
    hipMemcpyAsync(out + (size_t)MROWS * CH, g_info + 2 * CH, (size_t)2 * CH * sizeof(float),
                   hipMemcpyDeviceToDevice, stream);
}